// Round 1
// baseline (131.338 us; speedup 1.0000x reference)
//
#include <hip/hip_runtime.h>

// Problem constants (from reference): B=4096, I=30000, O=10000, I == 3*O.
#define BATCH 4096
#define INF   30000
#define OUTF  10000

// ---------------------------------------------------------------------------
// Kernel 1: gather the active diagonal band of weight into workspace.
// w_band[i] = weight[i/3, i]  (flat: (i/3)*INF + i), i in [0, INF)
// ---------------------------------------------------------------------------
__global__ void gather_band_kernel(const float* __restrict__ weight,
                                   float* __restrict__ w_band) {
    int i = blockIdx.x * blockDim.x + threadIdx.x;
    if (i < INF) {
        int row = i / 3;
        w_band[i] = weight[(size_t)row * INF + i];
    }
}

// ---------------------------------------------------------------------------
// Kernel 2: out[b,o] = sum_{j<3} x[b,3o+j] * w_band[3o+j] + bias[o]
// One thread handles 4 consecutive outputs = 12 consecutive input floats
// = 3 float4 loads of x + 3 float4 loads of band (L2-hot) + 1 float4 bias,
// one float4 store. Total threads = B * O/4 = 4096 * 2500 = 10,240,000.
// ---------------------------------------------------------------------------
#define GROUPS_PER_ROW (OUTF / 4)   // 2500

__global__ __launch_bounds__(256)
void banded_matvec_kernel(const float* __restrict__ x,
                          const float* __restrict__ w_band,
                          const float* __restrict__ bias,
                          float* __restrict__ out) {
    int t = blockIdx.x * blockDim.x + threadIdx.x;   // [0, B*GROUPS_PER_ROW)
    int b = t / GROUPS_PER_ROW;
    int r = t - b * GROUPS_PER_ROW;                  // group within row

    const float4* xv = reinterpret_cast<const float4*>(x + (size_t)b * INF + (size_t)r * 12);
    const float4* wv = reinterpret_cast<const float4*>(w_band + (size_t)r * 12);

    float4 x0 = xv[0], x1 = xv[1], x2 = xv[2];
    float4 w0 = wv[0], w1 = wv[1], w2 = wv[2];
    float4 bb = *reinterpret_cast<const float4*>(bias + (size_t)r * 4);

    float4 o4;
    o4.x = fmaf(x0.z, w0.z, fmaf(x0.y, w0.y, x0.x * w0.x)) + bb.x;
    o4.y = fmaf(x1.y, w1.y, fmaf(x1.x, w1.x, x0.w * w0.w)) + bb.y;
    o4.z = fmaf(x2.x, w2.x, fmaf(x1.w, w1.w, x1.z * w1.z)) + bb.z;
    o4.w = fmaf(x2.w, w2.w, fmaf(x2.z, w2.z, x2.y * w2.y)) + bb.w;

    *reinterpret_cast<float4*>(out + (size_t)b * OUTF + (size_t)r * 4) = o4;
}

extern "C" void kernel_launch(void* const* d_in, const int* in_sizes, int n_in,
                              void* d_out, int out_size, void* d_ws, size_t ws_size,
                              hipStream_t stream) {
    const float* x      = (const float*)d_in[0];   // [B, I]
    const float* weight = (const float*)d_in[1];   // [O, I]
    const float* bias   = (const float*)d_in[2];   // [O]
    float* out          = (float*)d_out;           // [B, O]
    float* w_band       = (float*)d_ws;            // INF floats = 120 KB

    // 1) gather band (30000 elements)
    {
        int threads = 256;
        int blocks = (INF + threads - 1) / threads;
        gather_band_kernel<<<blocks, threads, 0, stream>>>(weight, w_band);
    }

    // 2) main banded reduction: B*O/4 threads
    {
        int total = BATCH * GROUPS_PER_ROW;          // 10,240,000
        int threads = 256;
        int blocks = total / threads;                // 40,000 exactly
        banded_matvec_kernel<<<blocks, threads, 0, stream>>>(x, w_band, bias, out);
    }
}